// Round 1
// baseline (222.675 us; speedup 1.0000x reference)
//
#include <hip/hip_runtime.h>

// Problem constants (from reference)
#define B_   8192
#define NY_  8
#define MT_  32
#define RR_  16
constexpr float PAR_WIDTH  = 0.6f;
constexpr float MAX_LENGTH = 5.0f;

// Flat element counts
constexpr long N_SLOT  = (long)B_ * NY_ * MT_ * RR_ * 2;  // 67,108,864
constexpr long N_LW    = (long)B_ * NY_ * MT_ * RR_;      // 33,554,432
constexpr long N_CNT   = (long)B_ * NY_;                  // 65,536

// Output offsets (elements) in the concatenated d_out (all float32)
constexpr long OFF_SLOT = 0;
constexpr long OFF_LEN  = N_SLOT;
constexpr long OFF_WID  = N_SLOT + N_LW;
constexpr long OFF_CNT  = N_SLOT + 2 * N_LW;

// int32 -> float32 converting copy, 4 elems/thread/iter
__global__ void copy_i2f4(const int* __restrict__ in, float* __restrict__ out, long n4) {
    long i = (long)blockIdx.x * blockDim.x + threadIdx.x;
    long stride = (long)gridDim.x * blockDim.x;
    for (; i < n4; i += stride) {
        int4 v = reinterpret_cast<const int4*>(in)[i];
        float4 f;
        f.x = (float)v.x; f.y = (float)v.y; f.z = (float)v.z; f.w = (float)v.w;
        reinterpret_cast<float4*>(out)[i] = f;
    }
}

// float32 copy, 4 elems/thread/iter
__global__ void copy_f4(const float* __restrict__ in, float* __restrict__ out, long n4) {
    long i = (long)blockIdx.x * blockDim.x + threadIdx.x;
    long stride = (long)gridDim.x * blockDim.x;
    for (; i < n4; i += stride) {
        reinterpret_cast<float4*>(out)[i] = reinterpret_cast<const float4*>(in)[i];
    }
}

// One thread per batch element: convert+copy its barge_count row, then apply
// the sparse update logic on top of the already-copied outputs.
__global__ void update_kernel(const int*   __restrict__ sel,      // [B]
                              const float* __restrict__ bsz,      // [B,1,5]
                              const int*   __restrict__ ysel,     // [B]
                              const int*   __restrict__ bcnt,     // [B,NY]
                              const float* __restrict__ lens,     // [B,NY,MT,RR]
                              const float* __restrict__ wids,     // [B,NY,MT,RR]
                              float* __restrict__ out) {
    int b = blockIdx.x * blockDim.x + threadIdx.x;
    if (b >= B_) return;

    float* out_slot = out + OFF_SLOT;
    float* out_len  = out + OFF_LEN;
    float* out_wid  = out + OFF_WID;
    float* out_cnt  = out + OFF_CNT;

    // copy/convert this b's barge_count row
    #pragma unroll
    for (int j = 0; j < NY_; ++j)
        out_cnt[(long)b * NY_ + j] = (float)bcnt[(long)b * NY_ + j];

    const int y = ysel[b];
    const int s = bcnt[(long)b * NY_ + y];

    const long base = ((((long)b * NY_ + y) * MT_) + s) * RR_;
    const float blen = bsz[(long)b * 5 + 0];
    const float bwid = bsz[(long)b * 5 + 1];

    bool has_par_space = false;
    bool has_valid     = false;
    float maxv = -1e30f;
    int   maxi = 0;
    float total = 0.0f;

    #pragma unroll
    for (int r = 0; r < RR_; ++r) {
        const float wr = wids[base + r];
        const float lr = lens[base + r];
        const bool par = (wr <= PAR_WIDTH);
        has_par_space |= par;
        has_valid     |= (par && (wr != 0.0f));
        const float pl = par ? lr : -1.0f;
        if (pl > maxv) { maxv = pl; maxi = r; }  // first-max (strict >)
        total += lr;
    }

    const bool is_par_block = (bwid <= PAR_WIDTH);
    const bool par_alloc    = is_par_block && has_par_space;
    const bool has_existing = has_valid && par_alloc;

    const bool dir_mask  = has_existing && (maxv >= blen);
    const bool recons    = has_existing && (maxv <  blen);
    const bool allocable = (total - maxv + blen) <= MAX_LENGTH;
    const bool ra  = recons && allocable;
    const bool rna = recons && !allocable;

    if (dir_mask || ra) {
        out_slot[(base + maxi) * 2 + 1] = (float)sel[b];
        out_wid[base + maxi] = wids[base + maxi] + bwid;
        if (ra) out_len[base + maxi] = blen;
    }
    if (rna) {
        out_cnt[(long)b * NY_ + y] = (float)(s + 1);
        const int s2 = min(s + 1, MT_ - 1);
        const long base2 = ((((long)b * NY_ + y) * MT_) + s2) * RR_;
        out_slot[base2 * 2 + 0] = (float)sel[b];
        out_len[base2] = blen;
        out_wid[base2] = wids[base2] + bwid;
    }
}

extern "C" void kernel_launch(void* const* d_in, const int* in_sizes, int n_in,
                              void* d_out, int out_size, void* d_ws, size_t ws_size,
                              hipStream_t stream) {
    const int*   block_selection = (const int*)  d_in[0];
    const float* block_size      = (const float*)d_in[1];
    const int*   yard_selection  = (const int*)  d_in[2];
    const int*   barge_count     = (const int*)  d_in[3];
    const int*   barge_slot      = (const int*)  d_in[4];
    const float* lens            = (const float*)d_in[5];
    const float* wids            = (const float*)d_in[6];
    float* out = (float*)d_out;

    const int threads = 256;
    const int grid = 2048;  // grid-stride; ~8 blocks/CU

    // Bulk copies (convert ints to float for the harness's float32 view)
    copy_i2f4<<<grid, threads, 0, stream>>>(barge_slot, out + OFF_SLOT, N_SLOT / 4);
    copy_f4  <<<grid, threads, 0, stream>>>(lens,       out + OFF_LEN,  N_LW / 4);
    copy_f4  <<<grid, threads, 0, stream>>>(wids,       out + OFF_WID,  N_LW / 4);

    // Sparse updates (+ barge_count convert/copy), ordered after copies
    update_kernel<<<(B_ + threads - 1) / threads, threads, 0, stream>>>(
        block_selection, block_size, yard_selection, barge_count, lens, wids, out);
}